// Round 13
// baseline (585.559 us; speedup 1.0000x reference)
//
#include <hip/hip_runtime.h>

#define N_NODES 50000
#define N_PAD 50048 /* 391*128 */
#define NBY 391
#define N_EDGES 400000
#define EP (N_EDGES + N_NODES) /* 450000 with self loops */
#define N_GRAPHS 256
#define EMB 64
#define HID 128
#define HEADS 4
#define GDIM 256
#define NUM_CLASSES 20
#define EPS_BN 1e-5f
#define NEG_SLOPE 0.2f
#define NB_AGG 2048

typedef __attribute__((ext_vector_type(4))) float f32x4;
typedef _Float16 h8 __attribute__((ext_vector_type(8)));
typedef _Float16 h4 __attribute__((ext_vector_type(4)));
typedef _Float16 h2 __attribute__((ext_vector_type(2)));
typedef signed char c8 __attribute__((ext_vector_type(8)));

#define GLD(g, l)                                                              \
    __builtin_amdgcn_global_load_lds(                                          \
        (const __attribute__((address_space(1))) void*)(g),                    \
        (__attribute__((address_space(3))) void*)(l), 16, 0, 0)

// ---------------- CSR build (self-loops included) ----------------
__global__ void k_deg(const int* __restrict__ ei, int* __restrict__ deg) {
    int e = blockIdx.x * blockDim.x + threadIdx.x;
    if (e >= EP) return;
    int dst = (e < N_EDGES) ? ei[N_EDGES + e] : (e - N_EDGES);
    atomicAdd(&deg[dst], 1);
}

__global__ void k_scanA(const int* __restrict__ deg, int* __restrict__ incl, int* __restrict__ bsums) {
    __shared__ int sh[1024];
    int t = threadIdx.x;
    int i = blockIdx.x * 1024 + t;
    int v = (i < N_NODES) ? deg[i] : 0;
    int xv = v;
    sh[t] = xv;
    __syncthreads();
    for (int off = 1; off < 1024; off <<= 1) {
        int y = (t >= off) ? sh[t - off] : 0;
        __syncthreads();
        xv += y;
        sh[t] = xv;
        __syncthreads();
    }
    if (i < N_NODES) incl[i] = xv;
    if (t == 1023) bsums[blockIdx.x] = xv;
}

// scanB folded in: each block (uniform i>>10) sums the preceding block totals.
__global__ void k_scanC(const int* __restrict__ incl, const int* __restrict__ deg,
                        const int* __restrict__ bsums, int* __restrict__ offs) {
    int i = blockIdx.x * blockDim.x + threadIdx.x;
    int b = i >> 10;  // uniform within a 256-thread block
    int add = 0;
    for (int k = 0; k < b; k++) add += bsums[k];
    if (i < N_NODES) offs[i] = incl[i] - deg[i] + add;
    if (i == 0) offs[N_NODES] = EP;
}

__global__ void k_scatter(const int* __restrict__ ei, const int* __restrict__ offs,
                          int* __restrict__ cnt, int* __restrict__ csr) {
    int e = blockIdx.x * blockDim.x + threadIdx.x;
    if (e >= EP) return;
    int src, dst;
    if (e < N_EDGES) { src = ei[e]; dst = ei[N_EDGES + e]; }
    else { src = e - N_EDGES; dst = src; }
    int pos = atomicAdd(&cnt[dst], 1);
    csr[offs[dst] + pos] = src;
}

// ---------------- fused setup: fp16 weight conversions + wtil + bn/deg zeroing ----------------
__device__ __forceinline__ void cvt1(const float* __restrict__ in, _Float16* __restrict__ o, int i) {
    int f = i * 4;
    float4 v = *(const float4*)(in + f);
    h4 r;
    r[0] = (_Float16)v.x; r[1] = (_Float16)v.y; r[2] = (_Float16)v.z; r[3] = (_Float16)v.w;
    *(h4*)(o + f) = r;
}

__global__ __launch_bounds__(256) void k_setup(const float* __restrict__ W0, const float* __restrict__ as0,
                                               const float* __restrict__ ad0, const float* __restrict__ W1,
                                               const float* __restrict__ W2,
                                               _Float16* __restrict__ W0f, _Float16* __restrict__ W1f,
                                               _Float16* __restrict__ W2f,
                                               float* __restrict__ wtil,
                                               float* __restrict__ bn0, float* __restrict__ bn1,
                                               float* __restrict__ bn2,
                                               int* __restrict__ deg) {
    int b = blockIdx.x, t = threadIdx.x;
    if (b < 256) {                       // W1: 512x512 -> 65536 float4
        cvt1(W1, W1f, b * 256 + t);
    } else if (b < 288) {                // W0: 512x64 -> 8192 float4
        cvt1(W0, W0f, (b - 256) * 256 + t);
    } else if (b < 352) {                // W2: 128x512 -> 16384 float4
        cvt1(W2, W2f, (b - 288) * 256 + t);
    } else if (b == 352) {               // wtil = W0 projected onto a_src/a_dst
        int h = t >> 6, k = t & 63;
        float ss = 0.f, sd = 0.f;
        for (int c = 0; c < 128; c++) {
            float w = W0[(size_t)(h * 128 + c) * 64 + k];
            ss += w * as0[h * 128 + c];
            sd += w * ad0[h * 128 + c];
        }
        wtil[t] = ss;
        wtil[256 + t] = sd;
    } else if (b == 353) {               // zero the three BN accumulators
        for (int i = t; i < 1024; i += 256) { bn0[i] = 0.f; bn1[i] = 0.f; bn2[i] = 0.f; }
    } else {                             // zero deg+cnt (2*N_NODES ints = 25000 int4)
        int i4 = (b - 354) * 256 + t;
        if (i4 < 25000) ((int4*)deg)[i4] = make_int4(0, 0, 0, 0);
    }
}

// ---------------- fused node features + layer-0 logits + graph bounds ----------------
__global__ __launch_bounds__(256) void k_node_al0(const int* __restrict__ x,
                                                  const float* __restrict__ depth,
                                                  const float* __restrict__ emb_table,
                                                  const float* __restrict__ dw,
                                                  const float* __restrict__ db,
                                                  const float* __restrict__ wtil,
                                                  const int* __restrict__ batch,
                                                  _Float16* __restrict__ h16,
                                                  float* __restrict__ als, float* __restrict__ ald,
                                                  int* __restrict__ goffs) {
    int wid = threadIdx.x >> 6, lane = threadIdx.x & 63;
    int n = blockIdx.x * 4 + wid;
    if (n >= N_NODES) return;
    float v = emb_table[x[n] * EMB + lane] + depth[n] * dw[lane] + db[lane];
    h16[(size_t)n * 64 + lane] = (_Float16)v;
#pragma unroll
    for (int h = 0; h < 4; h++) {
        float ps = v * wtil[h * 64 + lane];
        float pd = v * wtil[256 + h * 64 + lane];
        for (int off = 32; off; off >>= 1) {
            ps += __shfl_xor(ps, off);
            pd += __shfl_xor(pd, off);
        }
        if (lane == 0) { als[n * 4 + h] = ps; ald[n * 4 + h] = pd; }
    }
    if (lane == 0) {
        int b = batch[n];
        int bp = (n == 0) ? -1 : batch[n - 1];
        for (int g = bp + 1; g <= b; g++) goffs[g] = n;
        if (n == N_NODES - 1) {
            for (int g = b + 1; g <= N_GRAPHS; g++) goffs[g] = N_NODES;
        }
    }
}

// ---------------- in-place BN+ELU on fp16 activations (M=512); 2 rows/iter ----------------
__global__ __launch_bounds__(256) void k_bnelu(_Float16* __restrict__ a,
                                               const float* __restrict__ sums,
                                               const float* __restrict__ gamma,
                                               const float* __restrict__ beta) {
    const int lane = threadIdx.x & 63;
    const int wid = threadIdx.x >> 6;
    const int c0 = lane * 8;
    const float invN = 1.f / (float)N_NODES;
    float sc[8], sh[8];
#pragma unroll
    for (int k = 0; k < 8; k += 4) {
        float4 s4 = *(const float4*)(sums + c0 + k);
        float4 q4 = *(const float4*)(sums + 512 + c0 + k);
        float4 g4 = *(const float4*)(gamma + c0 + k);
        float4 b4 = *(const float4*)(beta + c0 + k);
        float m, v;
        m = s4.x * invN; v = q4.x * invN - m * m;
        sc[k + 0] = g4.x * __frsqrt_rn(v + EPS_BN); sh[k + 0] = b4.x - m * sc[k + 0];
        m = s4.y * invN; v = q4.y * invN - m * m;
        sc[k + 1] = g4.y * __frsqrt_rn(v + EPS_BN); sh[k + 1] = b4.y - m * sc[k + 1];
        m = s4.z * invN; v = q4.z * invN - m * m;
        sc[k + 2] = g4.z * __frsqrt_rn(v + EPS_BN); sh[k + 2] = b4.z - m * sc[k + 2];
        m = s4.w * invN; v = q4.w * invN - m * m;
        sc[k + 3] = g4.w * __frsqrt_rn(v + EPS_BN); sh[k + 3] = b4.w - m * sc[k + 3];
    }
    // 2 rows per iteration (N even, start/stride even -> n+1 always valid)
    const int stride = gridDim.x * 8;
    for (int n = (blockIdx.x * 4 + wid) * 2; n < N_NODES; n += stride) {
        _Float16* p0 = a + (size_t)n * 512 + c0;
        _Float16* p1 = p0 + 512;
        h8 v0 = *(h8*)p0;
        h8 v1 = *(h8*)p1;
        h8 o0, o1;
#pragma unroll
        for (int k = 0; k < 8; k++) {
            float x0 = (float)v0[k] * sc[k] + sh[k];
            x0 = x0 > 0.f ? x0 : expm1f(x0);
            o0[k] = (_Float16)x0;
            float x1 = (float)v1[k] * sc[k] + sh[k];
            x1 = x1 > 0.f ? x1 : expm1f(x1);
            o1[k] = (_Float16)x1;
        }
        *(h8*)p0 = o0;
        *(h8*)p1 = o1;
    }
}

// layer-0 aggregate in h-space: QUARTER-WAVE per node; fp16 gather; 4-edge unroll.
__global__ __launch_bounds__(256) void k_agg0(const _Float16* __restrict__ h16,
                                              const float* __restrict__ als,
                                              const float* __restrict__ ald_g,
                                              const int* __restrict__ offs,
                                              const int* __restrict__ csr,
                                              _Float16* __restrict__ outh) {
    const int lane = threadIdx.x & 63;
    const int wwid = threadIdx.x >> 6;
    const int q = lane >> 4, l = lane & 15;
    const int gw = blockIdx.x * 4 + wwid;
    const int stride = gridDim.x * 16;
    for (int n = gw * 4 + q; n < N_NODES; n += stride) {
        int s0 = offs[n], s1 = offs[n + 1];
        float aldl = (l < 4) ? ald_g[n * 4 + l] : 0.f;
        float acc[4][4] = {};
        float den[4] = {};
        int e = s0;
        for (; e + 4 <= s1; e += 4) {
            int srcA = csr[e], srcB = csr[e + 1];
            int srcC = csr[e + 2], srcD = csr[e + 3];
            float wA = 0.f, wB = 0.f, wC = 0.f, wD = 0.f;
            if (l < 4) {
                float a1 = als[srcA * 4 + l] + aldl;
                a1 = a1 > 0.f ? a1 : NEG_SLOPE * a1;
                wA = expf(a1);
                float a2 = als[srcB * 4 + l] + aldl;
                a2 = a2 > 0.f ? a2 : NEG_SLOPE * a2;
                wB = expf(a2);
                float a3 = als[srcC * 4 + l] + aldl;
                a3 = a3 > 0.f ? a3 : NEG_SLOPE * a3;
                wC = expf(a3);
                float a4 = als[srcD * 4 + l] + aldl;
                a4 = a4 > 0.f ? a4 : NEG_SLOPE * a4;
                wD = expf(a4);
            }
            h4 vA = *(const h4*)(h16 + (size_t)srcA * 64 + l * 4);
            h4 vB = *(const h4*)(h16 + (size_t)srcB * 64 + l * 4);
            h4 vC = *(const h4*)(h16 + (size_t)srcC * 64 + l * 4);
            h4 vD = *(const h4*)(h16 + (size_t)srcD * 64 + l * 4);
            float vA0 = (float)vA[0], vA1 = (float)vA[1], vA2 = (float)vA[2], vA3 = (float)vA[3];
            float vB0 = (float)vB[0], vB1 = (float)vB[1], vB2 = (float)vB[2], vB3 = (float)vB[3];
            float vC0 = (float)vC[0], vC1 = (float)vC[1], vC2 = (float)vC[2], vC3 = (float)vC[3];
            float vD0 = (float)vD[0], vD1 = (float)vD[1], vD2 = (float)vD[2], vD3 = (float)vD[3];
#pragma unroll
            for (int h = 0; h < 4; h++) {
                float whA = __shfl(wA, q * 16 + h);
                float whB = __shfl(wB, q * 16 + h);
                float whC = __shfl(wC, q * 16 + h);
                float whD = __shfl(wD, q * 16 + h);
                den[h] += (whA + whB) + (whC + whD);
                acc[h][0] += whA * vA0 + whB * vB0 + whC * vC0 + whD * vD0;
                acc[h][1] += whA * vA1 + whB * vB1 + whC * vC1 + whD * vD1;
                acc[h][2] += whA * vA2 + whB * vB2 + whC * vC2 + whD * vD2;
                acc[h][3] += whA * vA3 + whB * vB3 + whC * vC3 + whD * vD3;
            }
        }
        for (; e < s1; e++) {
            int src = csr[e];
            float w = 0.f;
            if (l < 4) {
                float a1 = als[src * 4 + l] + aldl;
                a1 = a1 > 0.f ? a1 : NEG_SLOPE * a1;
                w = expf(a1);
            }
            h4 v = *(const h4*)(h16 + (size_t)src * 64 + l * 4);
            float v0 = (float)v[0], v1 = (float)v[1], v2 = (float)v[2], v3 = (float)v[3];
#pragma unroll
            for (int h = 0; h < 4; h++) {
                float wh = __shfl(w, q * 16 + h);
                den[h] += wh;
                acc[h][0] += wh * v0;
                acc[h][1] += wh * v1;
                acc[h][2] += wh * v2;
                acc[h][3] += wh * v3;
            }
        }
#pragma unroll
        for (int h = 0; h < 4; h++) {
            float id = 1.f / den[h];
            h4 hv;
            hv[0] = (_Float16)(acc[h][0] * id);
            hv[1] = (_Float16)(acc[h][1] * id);
            hv[2] = (_Float16)(acc[h][2] * id);
            hv[3] = (_Float16)(acc[h][3] * id);
            *(h4*)(outh + (size_t)n * 256 + h * 64 + l * 4) = hv;
        }
    }
}

// layer-0 block-diag fp16 MFMA GEMM (dbuf prefetch) + fused BN-stats epilogue
__global__ __launch_bounds__(256) void k_gemm0h(const _Float16* __restrict__ A,
                                                const _Float16* __restrict__ W,
                                                const float* __restrict__ bias,
                                                _Float16* __restrict__ outA,
                                                float* __restrict__ bnacc) {
    __shared__ h8 sA[2][512], sW[2][512];
    const int nbx = gridDim.x;
    const int d = blockIdx.y * nbx + blockIdx.x;
    const int by = (d / (8 * nbx)) * 8 + (d & 7);
    const int bx = (d >> 3) % nbx;
    if (by >= NBY) return;
    const int hd = bx;
    const int t = threadIdx.x;
    const int lane = t & 63;
    const int wid = t >> 6;
    const int wm = wid >> 1, wn = wid & 1;
    const int r0 = by * 128;
    const int l15 = lane & 15, quad = lane >> 4;
    f32x4 acc[4][4] = {};
    auto stage = [&](int buf, int kb) {
#pragma unroll
        for (int r = 0; r < 2; r++) {
            int c = r * 256 + t;
            int row = c >> 2, q = c & 3;
            size_t gA = ((size_t)(r0 + row) * 256 + hd * 64 + kb) * 2 + q * 16;
            size_t gW = ((size_t)(hd * 128 + row) * 64 + kb) * 2 + q * 16;
            GLD((const char*)A + gA, (char*)&sA[buf][0] + c * 16);
            GLD((const char*)W + gW, (char*)&sW[buf][0] + c * 16);
        }
    };
    stage(0, 0);
    __syncthreads();
#pragma unroll
    for (int ki = 0; ki < 2; ki++) {
        int cur = ki & 1;
        if (ki + 1 < 2) stage(cur ^ 1, (ki + 1) * 32);
        h8 a[4], w[4];
#pragma unroll
        for (int i = 0; i < 4; i++) {
            a[i] = sA[cur][(wm * 64 + i * 16 + l15) * 4 + quad];
            w[i] = sW[cur][(wn * 64 + i * 16 + l15) * 4 + quad];
        }
#pragma unroll
        for (int i = 0; i < 4; i++)
#pragma unroll
            for (int j = 0; j < 4; j++)
                acc[i][j] = __builtin_amdgcn_mfma_f32_16x16x32_f16(a[i], w[j], acc[i][j], 0, 0, 0);
        __syncthreads();
    }
    float colsum[4] = {}, colsq[4] = {};
#pragma unroll
    for (int i = 0; i < 4; i++) {
        int gr = r0 + wm * 64 + i * 16 + quad * 4;
#pragma unroll
        for (int j = 0; j < 4; j++) {
            int gc = hd * 128 + wn * 64 + j * 16 + l15;
            float bv = bias[gc];
#pragma unroll
            for (int rg = 0; rg < 4; rg++) {
                int rr = gr + rg;
                if (rr < N_NODES) {
                    float o = acc[i][j][rg] + bv;
                    outA[(size_t)rr * 512 + gc] = (_Float16)o;
                    colsum[j] += o;
                    colsq[j] += o * o;
                }
            }
        }
    }
#pragma unroll
    for (int j = 0; j < 4; j++) {
        colsum[j] += __shfl_xor(colsum[j], 16);
        colsum[j] += __shfl_xor(colsum[j], 32);
        colsq[j] += __shfl_xor(colsq[j], 16);
        colsq[j] += __shfl_xor(colsq[j], 32);
    }
    float* sS = (float*)&sA[0][0];
    float* sQ = (float*)&sW[0][0];
    __syncthreads();
    if (quad == 0) {
#pragma unroll
        for (int j = 0; j < 4; j++) {
            int c = wn * 64 + j * 16 + l15;
            sS[c * 2 + wm] = colsum[j];
            sQ[c * 2 + wm] = colsq[j];
        }
    }
    __syncthreads();
    if (t < 128) {
        atomicAdd(bnacc + hd * 128 + t, sS[t * 2] + sS[t * 2 + 1]);
        atomicAdd(bnacc + 512 + hd * 128 + t, sQ[t * 2] + sQ[t * 2 + 1]);
    }
}

// ---------------- layer-1 fp16 MFMA GEMM with int8 row-block-quantized output ----------------
__global__ __launch_bounds__(256) void k_gemm_q8(const _Float16* __restrict__ A,
                                                 const _Float16* __restrict__ W,
                                                 const float* __restrict__ a_src,
                                                 const float* __restrict__ a_dst,
                                                 float* __restrict__ als_g,
                                                 float* __restrict__ ald_g,
                                                 signed char* __restrict__ out8,
                                                 _Float16* __restrict__ scl,
                                                 int K, int M, int heads) {
    __shared__ h8 sA[2][512], sW[2][512];
    const int nbx = gridDim.x;
    const int d = blockIdx.y * nbx + blockIdx.x;
    const int by = (d / (8 * nbx)) * 8 + (d & 7);
    const int bx = (d >> 3) % nbx;
    if (by >= NBY) return;
    const int t = threadIdx.x;
    const int lane = t & 63;
    const int wid = t >> 6;
    const int wm = wid >> 1, wn = wid & 1;
    const int r0 = by * 128, c0 = bx * 128;
    const int l15 = lane & 15, quad = lane >> 4;
    f32x4 acc[4][4] = {};
    auto stage = [&](int buf, int kb) {
#pragma unroll
        for (int r = 0; r < 2; r++) {
            int c = r * 256 + t;
            int row = c >> 2, q = c & 3;
            size_t gA = ((size_t)(r0 + row) * K + kb) * 2 + q * 16;
            size_t gW = ((size_t)(c0 + row) * K + kb) * 2 + q * 16;
            GLD((const char*)A + gA, (char*)&sA[buf][0] + c * 16);
            GLD((const char*)W + gW, (char*)&sW[buf][0] + c * 16);
        }
    };
    stage(0, 0);
    __syncthreads();
    const int nkb = K >> 5;
    for (int ki = 0; ki < nkb; ki++) {
        int cur = ki & 1;
        if (ki + 1 < nkb) stage(cur ^ 1, (ki + 1) * 32);
        h8 a[4], w[4];
#pragma unroll
        for (int i = 0; i < 4; i++) {
            a[i] = sA[cur][(wm * 64 + i * 16 + l15) * 4 + quad];
            w[i] = sW[cur][(wn * 64 + i * 16 + l15) * 4 + quad];
        }
#pragma unroll
        for (int i = 0; i < 4; i++)
#pragma unroll
            for (int j = 0; j < 4; j++)
                acc[i][j] = __builtin_amdgcn_mfma_f32_16x16x32_f16(a[i], w[j], acc[i][j], 0, 0, 0);
        __syncthreads();
    }
    // ---- per-(row, col-block) absmax -> scale -> int8 quantize ----
    float* sAm = (float*)&sA[0][0];  // 256 floats
    {
        float amax[4][4];
#pragma unroll
        for (int i = 0; i < 4; i++)
#pragma unroll
            for (int rg = 0; rg < 4; rg++) {
                float m = 0.f;
#pragma unroll
                for (int j = 0; j < 4; j++) m = fmaxf(m, fabsf(acc[i][j][rg]));
#pragma unroll
                for (int mk = 1; mk < 16; mk <<= 1) m = fmaxf(m, __shfl_xor(m, mk));
                amax[i][rg] = m;
            }
        if (l15 == 0) {
#pragma unroll
            for (int i = 0; i < 4; i++)
#pragma unroll
                for (int rg = 0; rg < 4; rg++) {
                    int ri = wm * 64 + i * 16 + quad * 4 + rg;
                    sAm[ri * 2 + wn] = amax[i][rg];
                }
        }
    }
    __syncthreads();
#pragma unroll
    for (int i = 0; i < 4; i++) {
        int gr = r0 + wm * 64 + i * 16 + quad * 4;
#pragma unroll
        for (int rg = 0; rg < 4; rg++) {
            int ri = wm * 64 + i * 16 + quad * 4 + rg;
            float amax = fmaxf(sAm[ri * 2], sAm[ri * 2 + 1]);
            _Float16 s_h = (_Float16)(amax * (1.f / 127.f));
            float s_r = (float)s_h;
            float inv = s_r > 0.f ? 1.f / s_r : 0.f;
            int rr = gr + rg;
            if (rr < N_NODES) {
                if (wn == 0 && l15 == 0) scl[(size_t)rr * 4 + bx] = s_h;
#pragma unroll
                for (int j = 0; j < 4; j++) {
                    int gc = c0 + wn * 64 + j * 16 + l15;
                    int q = (int)rintf(acc[i][j][rg] * inv);
                    q = q > 127 ? 127 : (q < -127 ? -127 : q);
                    out8[(size_t)rr * 512 + gc] = (signed char)q;
                }
            }
        }
    }
    __syncthreads();
    // ---- exact fp32 attention-logit epilogue (unchanged) ----
    const int hd = bx;
    float ps[4][4] = {}, pd[4][4] = {};
#pragma unroll
    for (int j = 0; j < 4; j++) {
        int ch = wn * 64 + j * 16 + l15;
        float av = a_src[hd * 128 + ch];
        float dv = a_dst[hd * 128 + ch];
#pragma unroll
        for (int i = 0; i < 4; i++)
#pragma unroll
            for (int rg = 0; rg < 4; rg++) {
                ps[i][rg] += acc[i][j][rg] * av;
                pd[i][rg] += acc[i][j][rg] * dv;
            }
    }
#pragma unroll
    for (int m = 1; m < 16; m <<= 1)
#pragma unroll
        for (int i = 0; i < 4; i++)
#pragma unroll
            for (int rg = 0; rg < 4; rg++) {
                ps[i][rg] += __shfl_xor(ps[i][rg], m);
                pd[i][rg] += __shfl_xor(pd[i][rg], m);
            }
    float* sS = (float*)&sA[0][0];
    float* sD = (float*)&sW[0][0];
    if (l15 == 0) {
#pragma unroll
        for (int i = 0; i < 4; i++)
#pragma unroll
            for (int rg = 0; rg < 4; rg++) {
                int ri = wm * 64 + i * 16 + quad * 4 + rg;
                sS[ri * 2 + wn] = ps[i][rg];
                sD[ri * 2 + wn] = pd[i][rg];
            }
    }
    __syncthreads();
    if (t < 128) {
        int row = r0 + t;
        if (row < N_NODES) {
            als_g[row * heads + hd] = sS[t * 2] + sS[t * 2 + 1];
            ald_g[row * heads + hd] = sD[t * 2] + sD[t * 2 + 1];
        }
    }
}

// ---------------- fp16 MFMA GEMM (dbuf prefetch) + fused attention-logit epilogue ----------------
__global__ __launch_bounds__(256) void k_gemm_mfma(const _Float16* __restrict__ A,
                                                   const _Float16* __restrict__ W,
                                                   const float* __restrict__ a_src,
                                                   const float* __restrict__ a_dst,
                                                   float* __restrict__ als_g,
                                                   float* __restrict__ ald_g,
                                                   _Float16* __restrict__ out,
                                                   int K, int M, int heads) {
    __shared__ h8 sA[2][512], sW[2][512];
    const int nbx = gridDim.x;
    const int d = blockIdx.y * nbx + blockIdx.x;
    const int by = (d / (8 * nbx)) * 8 + (d & 7);
    const int bx = (d >> 3) % nbx;
    if (by >= NBY) return;
    const int t = threadIdx.x;
    const int lane = t & 63;
    const int wid = t >> 6;
    const int wm = wid >> 1, wn = wid & 1;
    const int r0 = by * 128, c0 = bx * 128;
    const int l15 = lane & 15, quad = lane >> 4;
    f32x4 acc[4][4] = {};
    auto stage = [&](int buf, int kb) {
#pragma unroll
        for (int r = 0; r < 2; r++) {
            int c = r * 256 + t;
            int row = c >> 2, q = c & 3;
            size_t gA = ((size_t)(r0 + row) * K + kb) * 2 + q * 16;
            size_t gW = ((size_t)(c0 + row) * K + kb) * 2 + q * 16;
            GLD((const char*)A + gA, (char*)&sA[buf][0] + c * 16);
            GLD((const char*)W + gW, (char*)&sW[buf][0] + c * 16);
        }
    };
    stage(0, 0);
    __syncthreads();
    const int nkb = K >> 5;
    for (int ki = 0; ki < nkb; ki++) {
        int cur = ki & 1;
        if (ki + 1 < nkb) stage(cur ^ 1, (ki + 1) * 32);
        h8 a[4], w[4];
#pragma unroll
        for (int i = 0; i < 4; i++) {
            a[i] = sA[cur][(wm * 64 + i * 16 + l15) * 4 + quad];
            w[i] = sW[cur][(wn * 64 + i * 16 + l15) * 4 + quad];
        }
#pragma unroll
        for (int i = 0; i < 4; i++)
#pragma unroll
            for (int j = 0; j < 4; j++)
                acc[i][j] = __builtin_amdgcn_mfma_f32_16x16x32_f16(a[i], w[j], acc[i][j], 0, 0, 0);
        __syncthreads();
    }
#pragma unroll
    for (int i = 0; i < 4; i++) {
        int gr = r0 + wm * 64 + i * 16 + quad * 4;
#pragma unroll
        for (int j = 0; j < 4; j++) {
            int gc = c0 + wn * 64 + j * 16 + l15;
#pragma unroll
            for (int rg = 0; rg < 4; rg++) {
                int rr = gr + rg;
                if (rr < N_NODES) out[(size_t)rr * M + gc] = (_Float16)acc[i][j][rg];
            }
        }
    }
    const int hd = bx;
    float ps[4][4] = {}, pd[4][4] = {};
#pragma unroll
    for (int j = 0; j < 4; j++) {
        int ch = wn * 64 + j * 16 + l15;
        float av = a_src[hd * 128 + ch];
        float dv = a_dst[hd * 128 + ch];
#pragma unroll
        for (int i = 0; i < 4; i++)
#pragma unroll
            for (int rg = 0; rg < 4; rg++) {
                ps[i][rg] += acc[i][j][rg] * av;
                pd[i][rg] += acc[i][j][rg] * dv;
            }
    }
#pragma unroll
    for (int m = 1; m < 16; m <<= 1)
#pragma unroll
        for (int i = 0; i < 4; i++)
#pragma unroll
            for (int rg = 0; rg < 4; rg++) {
                ps[i][rg] += __shfl_xor(ps[i][rg], m);
                pd[i][rg] += __shfl_xor(pd[i][rg], m);
            }
    float* sS = (float*)&sA[0][0];
    float* sD = (float*)&sW[0][0];
    if (l15 == 0) {
#pragma unroll
        for (int i = 0; i < 4; i++)
#pragma unroll
            for (int rg = 0; rg < 4; rg++) {
                int ri = wm * 64 + i * 16 + quad * 4 + rg;
                sS[ri * 2 + wn] = ps[i][rg];
                sD[ri * 2 + wn] = pd[i][rg];
            }
    }
    __syncthreads();
    if (t < 128) {
        int row = r0 + t;
        if (row < N_NODES) {
            als_g[row * heads + hd] = sS[t * 2] + sS[t * 2 + 1];
            ald_g[row * heads + hd] = sD[t * 2] + sD[t * 2 + 1];
        }
    }
}

// ---------------- layer-1 segment-softmax aggregation over int8 rows ----------------
// Dequant folded into LDS staging; den via 16-lane group reduce; 16-edge unroll
// doubles line-level MLP (128 lines in flight/wave, matching the fp16 version).
__global__ __launch_bounds__(256) void k_agg512(const signed char* __restrict__ x8,
                                                const _Float16* __restrict__ scl,
                                                const float* __restrict__ als,
                                                const float* __restrict__ ald_g,
                                                const int* __restrict__ offs,
                                                const int* __restrict__ csr,
                                                const float* __restrict__ bias,
                                                _Float16* __restrict__ out16,
                                                float* __restrict__ bnacc) {
    __shared__ float pool[4][1024];
    const int wid = threadIdx.x >> 6, lane = threadIdx.x & 63;
    int* s_src = (int*)&pool[wid][0];
    float* s_w = &pool[wid][64];      // raw softmax weights [4][64]
    float* s_ws = &pool[wid][320];    // scale-folded weights [4][64]
    const int gw = blockIdx.x * 4 + wid;
    const int nw = gridDim.x * 4;
    const int hh = lane >> 4;   // head / col-block owning cols [lane*8, lane*8+8)
    const int l15 = lane & 15;
    const int c0 = lane * 8;
    float bias8[8];
#pragma unroll
    for (int k = 0; k < 8; k++) bias8[k] = bias[c0 + k];
    float bns[8] = {}, bnq[8] = {};
    for (int n = gw; n < N_NODES; n += nw) {
        int s0 = offs[n], s1 = offs[n + 1];
        float4 aldv = *(const float4*)(ald_g + n * 4);
        float a[8] = {};
        float den = 0.f;
        for (int base = s0; base < s1; base += 64) {
            int j = base + lane;
            int srcj = 0;
            float w0 = 0.f, w1 = 0.f, w2 = 0.f, w3 = 0.f;
            float sc0 = 0.f, sc1 = 0.f, sc2 = 0.f, sc3 = 0.f;
            if (j < s1) {
                srcj = csr[j];
                float4 alv = *(const float4*)(als + srcj * 4);
                h4 sc4 = *(const h4*)(scl + (size_t)srcj * 4);
                float e0 = alv.x + aldv.x; e0 = e0 > 0.f ? e0 : NEG_SLOPE * e0;
                float e1 = alv.y + aldv.y; e1 = e1 > 0.f ? e1 : NEG_SLOPE * e1;
                float e2 = alv.z + aldv.z; e2 = e2 > 0.f ? e2 : NEG_SLOPE * e2;
                float e3 = alv.w + aldv.w; e3 = e3 > 0.f ? e3 : NEG_SLOPE * e3;
                w0 = expf(e0); w1 = expf(e1); w2 = expf(e2); w3 = expf(e3);
                sc0 = (float)sc4[0]; sc1 = (float)sc4[1];
                sc2 = (float)sc4[2]; sc3 = (float)sc4[3];
            }
            s_src[lane] = srcj;
            s_w[0 * 64 + lane] = w0;
            s_w[1 * 64 + lane] = w1;
            s_w[2 * 64 + lane] = w2;
            s_w[3 * 64 + lane] = w3;
            s_ws[0 * 64 + lane] = w0 * sc0;
            s_ws[1 * 64 + lane] = w1 * sc1;
            s_ws[2 * 64 + lane] = w2 * sc2;
            s_ws[3 * 64 + lane] = w3 * sc3;
            // den for this chunk: each 16-lane head-group sums its 64 raw weights
            {
                float4 dw = *(const float4*)&s_w[hh * 64 + l15 * 4];
                float ds = (dw.x + dw.y) + (dw.z + dw.w);
                ds += __shfl_xor(ds, 1);
                ds += __shfl_xor(ds, 2);
                ds += __shfl_xor(ds, 4);
                ds += __shfl_xor(ds, 8);
                den += ds;
            }
            int cend = min(64, s1 - base);
            int e = 0;
            for (; e + 16 <= cend; e += 16) {
                c8 v[16];
#pragma unroll
                for (int u = 0; u < 16; u++)
                    v[u] = *(const c8*)(x8 + (size_t)s_src[e + u] * 512 + c0);
#pragma unroll
                for (int u = 0; u < 16; u++) {
                    float ws = s_ws[hh * 64 + e + u];
#pragma unroll
                    for (int k = 0; k < 8; k++) a[k] += ws * (float)v[u][k];
                }
            }
            for (; e + 4 <= cend; e += 4) {
                c8 v[4];
#pragma unroll
                for (int u = 0; u < 4; u++)
                    v[u] = *(const c8*)(x8 + (size_t)s_src[e + u] * 512 + c0);
#pragma unroll
                for (int u = 0; u < 4; u++) {
                    float ws = s_ws[hh * 64 + e + u];
#pragma unroll
                    for (int k = 0; k < 8; k++) a[k] += ws * (float)v[u][k];
                }
            }
            for (; e < cend; e++) {
                c8 v = *(const c8*)(x8 + (size_t)s_src[e] * 512 + c0);
                float ws = s_ws[hh * 64 + e];
#pragma unroll
                for (int k = 0; k < 8; k++) a[k] += ws * (float)v[k];
            }
        }
        float id = 1.f / den;
        h8 ov;
#pragma unroll
        for (int k = 0; k < 8; k++) {
            float o = a[k] * id + bias8[k];
            ov[k] = (_Float16)o;
            bns[k] += o;
            bnq[k] += o * o;
        }
        *(h8*)(out16 + (size_t)n * 512 + c0) = ov;
    }
#pragma unroll
    for (int k = 0; k < 8; k++) {
        pool[wid][c0 + k] = bns[k];
        pool[wid][512 + c0 + k] = bnq[k];
    }
    __syncthreads();
    for (int t = threadIdx.x; t < 1024; t += 256)
        atomicAdd(bnacc + t, pool[0][t] + pool[1][t] + pool[2][t] + pool[3][t]);
}

// ---------------- layer-2 tail aggregation (1 head, fp16 in/out) ----------------
__global__ __launch_bounds__(256) void k_agg128(const _Float16* __restrict__ xf,
                                                const float* __restrict__ als,
                                                const float* __restrict__ ald_g,
                                                const int* __restrict__ offs,
                                                const int* __restrict__ csr,
                                                const float* __restrict__ bias,
                                                _Float16* __restrict__ out_h,
                                                float* __restrict__ bnacc) {
    __shared__ float pool[4][256];
    const int wid = threadIdx.x >> 6, lane = threadIdx.x & 63;
    int* s_src = (int*)&pool[wid][0];
    float* s_w = &pool[wid][64];
    const int gw = blockIdx.x * 4 + wid;
    const int nw = gridDim.x * 4;
    const int c = lane * 2;
    const float2 biasv = *(const float2*)(bias + c);
    float bns0 = 0.f, bns1 = 0.f, bnq0 = 0.f, bnq1 = 0.f;
    for (int n = gw; n < N_NODES; n += nw) {
        int s0 = offs[n], s1 = offs[n + 1];
        float aldv = ald_g[n];
        float ax = 0.f, ay = 0.f, den = 0.f;
        for (int base = s0; base < s1; base += 64) {
            int j = base + lane;
            int srcj = 0;
            float alv = 0.f;
            if (j < s1) { srcj = csr[j]; alv = als[srcj]; }
            float e0 = alv + aldv;
            e0 = e0 > 0.f ? e0 : NEG_SLOPE * e0;
            s_src[lane] = srcj;
            s_w[lane] = expf(e0);
            int cend = min(64, s1 - base);
            int e = 0;
            for (; e + 8 <= cend; e += 8) {
                h2 v[8];
                float w[8];
#pragma unroll
                for (int u = 0; u < 8; u++) {
                    v[u] = *(const h2*)(xf + (size_t)s_src[e + u] * 128 + c);
                    w[u] = s_w[e + u];
                }
#pragma unroll
                for (int u = 0; u < 8; u++) {
                    den += w[u];
                    ax += w[u] * (float)v[u][0];
                    ay += w[u] * (float)v[u][1];
                }
            }
            for (; e < cend; e++) {
                h2 v = *(const h2*)(xf + (size_t)s_src[e] * 128 + c);
                float w = s_w[e];
                den += w;
                ax += w * (float)v[0];
                ay += w * (float)v[1];
            }
        }
        float id = 1.f / den;
        float ox = ax * id + biasv.x;
        float oy = ay * id + biasv.y;
        h2 oh;
        oh[0] = (_Float16)ox;
        oh[1] = (_Float16)oy;
        *(h2*)(out_h + (size_t)n * 128 + c) = oh;
        bns0 += ox; bnq0 += ox * ox;
        bns1 += oy; bnq1 += oy * oy;
    }
    pool[wid][c] = bns0; pool[wid][c + 1] = bns1;
    pool[wid][128 + c] = bnq0; pool[wid][128 + c + 1] = bnq1;
    __syncthreads();
    {
        int t = threadIdx.x;
        atomicAdd(bnacc + t, pool[0][t] + pool[1][t] + pool[2][t] + pool[3][t]);
    }
}

// ---------------- fused BN+ELU + mean/max pool + classifier (fp16 C) ----------------
__global__ __launch_bounds__(256) void k_poolclassify(const _Float16* __restrict__ C,
                                                      const float* __restrict__ bnsums,
                                                      const float* __restrict__ gamma,
                                                      const float* __restrict__ beta,
                                                      const int* __restrict__ goffs,
                                                      const float* __restrict__ cw1, const float* __restrict__ cb1,
                                                      const float* __restrict__ cw2, const float* __restrict__ cb2,
                                                      float* __restrict__ out) {
    __shared__ float er[256];
    __shared__ float red[256];
    int g = blockIdx.x, t = threadIdx.x;
    int c = t & 127, half = t >> 7;
    const float invN = 1.f / (float)N_NODES;
    float m = bnsums[c] * invN;
    float var = bnsums[128 + c] * invN - m * m;
    float sc = gamma[c] * __frsqrt_rn(var + EPS_BN);
    float sh = beta[c] - m * sc;
    int s = goffs[g], e = goffs[g + 1];
    float sum = 0.f, mx = -INFINITY;
    for (int n = s + half; n < e; n += 2) {
        float x = (float)C[(size_t)n * 128 + c] * sc + sh;
        x = x > 0.f ? x : expm1f(x);
        sum += x;
        mx = fmaxf(mx, x);
    }
    red[t] = sum;
    __syncthreads();
    float sumT = red[c] + red[128 + c];
    __syncthreads();
    red[t] = mx;
    __syncthreads();
    float mxT = fmaxf(red[c], red[128 + c]);
    int cnt = e - s;
    if (half == 0) {
        er[c] = sumT / (float)max(cnt, 1);
        er[128 + c] = mxT;
    }
    __syncthreads();
    float acc = cb1[t];
    for (int k = 0; k < 256; k++) acc += er[k] * cw1[t * 256 + k];
    __syncthreads();
    red[t] = fmaxf(acc, 0.f);
    __syncthreads();
    if (t < NUM_CLASSES) {
        float o = cb2[t];
        for (int k = 0; k < 256; k++) o += red[k] * cw2[t * 256 + k];
        out[g * NUM_CLASSES + t] = o;
    }
}

// ---------------- driver ----------------
extern "C" void kernel_launch(void* const* d_in, const int* in_sizes, int n_in,
                              void* d_out, int out_size, void* d_ws, size_t ws_size,
                              hipStream_t stream) {
    (void)in_sizes; (void)n_in; (void)out_size; (void)ws_size;
    const int* x = (const int*)d_in[0];
    const int* ei = (const int*)d_in[1];
    const float* depth = (const float*)d_in[2];
    const int* batch = (const int*)d_in[3];
    const float* emb_table = (const float*)d_in[4];
    const float* depth_w = (const float*)d_in[5];
    const float* depth_b = (const float*)d_in[6];
    const float* W0 = (const float*)d_in[7];
    const float* as0 = (const float*)d_in[8];
    const float* ad0 = (const float*)d_in[9];
    const float* b0 = (const float*)d_in[10];
    const float* g0 = (const float*)d_in[11];
    const float* be0 = (const float*)d_in[12];
    const float* W1 = (const float*)d_in[13];
    const float* as1 = (const float*)d_in[14];
    const float* ad1 = (const float*)d_in[15];
    const float* b1 = (const float*)d_in[16];
    const float* g1 = (const float*)d_in[17];
    const float* be1 = (const float*)d_in[18];
    const float* W2 = (const float*)d_in[19];
    const float* as2 = (const float*)d_in[20];
    const float* ad2 = (const float*)d_in[21];
    const float* b2 = (const float*)d_in[22];
    const float* g2 = (const float*)d_in[23];
    const float* be2 = (const float*)d_in[24];
    const float* cw1 = (const float*)d_in[25];
    const float* cb1 = (const float*)d_in[26];
    const float* cw2 = (const float*)d_in[27];
    const float* cb2 = (const float*)d_in[28];
    float* out = (float*)d_out;

    // workspace carve (~106 MB, well under the proven ws_size >= 211,469,440 B)
    size_t off = 0;
    char* base = (char*)d_ws;
    auto carve = [&](size_t bytes) -> void* {
        void* p = base + off;
        off += (bytes + 255) & ~(size_t)255;
        return p;
    };
    // B region (51.2 MB): layer-0 {h16 [N,64] fp16 | hth [N_PAD,256] fp16};
    // layer-1 {x8 int8 [N,512] (25.6MB) | scales fp16 [N,4] @+26MB};
    // layer-2 GEMM out fp16 [N,128] (12.8MB, x8 dead by then).
    float* B = (float*)carve((size_t)N_NODES * 512 * 2);
    _Float16* A16 = (_Float16*)carve((size_t)N_PAD * 512 * 2);  // 51.25 MB
    _Float16* W0f = (_Float16*)carve((size_t)512 * 64 * 2);
    _Float16* W1f = (_Float16*)carve((size_t)512 * 512 * 2);
    _Float16* W2f = (_Float16*)carve((size_t)128 * 512 * 2);
    float* als = (float*)carve((size_t)N_NODES * HEADS * 4);
    float* ald = (float*)carve((size_t)N_NODES * HEADS * 4);
    float* bn0 = (float*)carve(1024 * 4);
    float* bn1 = (float*)carve(1024 * 4);
    float* bn2 = (float*)carve(1024 * 4);
    float* wtil = (float*)carve(512 * 4);
    int* deg = (int*)carve((size_t)2 * N_NODES * 4);  // deg + cnt contiguous (zeroed in k_setup)
    int* cnt = deg + N_NODES;
    int* incl = (int*)carve((size_t)N_NODES * 4);
    int* offs = (int*)carve((size_t)(N_NODES + 1) * 4);
    int* bsums = (int*)carve(64 * 4);
    int* csr = (int*)carve((size_t)EP * 4);
    int* goffs = (int*)carve((size_t)(N_GRAPHS + 1) * 4);

    _Float16* h16 = (_Float16*)B;
    _Float16* hth = (_Float16*)((char*)B + (size_t)N_NODES * 64 * 2);
    signed char* X8 = (signed char*)B;                              // layer-1 int8 stream
    _Float16* scl = (_Float16*)((char*)B + (26u << 20));            // 400 KB scale table
    _Float16* Bh = (_Float16*)B;                                    // layer-2 fp16 [N,128]
    _Float16* C = (_Float16*)A16;     // layer-2 fp16 scratch reuses A16 region

    const int TPB = 256;
    int gbN = (N_NODES + TPB - 1) / TPB;
    int gbE = (EP + TPB - 1) / TPB;
    int nbScan = (N_NODES + 1023) / 1024;
    int gbNode4 = (N_NODES + 3) / 4;
    dim3 g512(4, 392);  // swizzled: 392 = ceil(391/8)*8
    dim3 g128(1, 391);

    k_setup<<<452, TPB, 0, stream>>>(W0, as0, ad0, W1, W2, W0f, W1f, W2f, wtil,
                                     bn0, bn1, bn2, deg);
    k_deg<<<gbE, TPB, 0, stream>>>(ei, deg);
    k_scanA<<<nbScan, 1024, 0, stream>>>(deg, incl, bsums);
    k_scanC<<<gbN, TPB, 0, stream>>>(incl, deg, bsums, offs);
    k_scatter<<<gbE, TPB, 0, stream>>>(ei, offs, cnt, csr);

    // ---- layer 0 (fused node features + logits + graph bounds; h-space aggregation) ----
    k_node_al0<<<gbNode4, TPB, 0, stream>>>(x, depth, emb_table, depth_w, depth_b, wtil,
                                            batch, h16, als, ald, goffs);
    k_agg0<<<NB_AGG, TPB, 0, stream>>>(h16, als, ald, offs, csr, hth);
    k_gemm0h<<<g512, TPB, 0, stream>>>(hth, W0f, b0, A16, bn0);
    k_bnelu<<<2048, TPB, 0, stream>>>(A16, bn0, g0, be0);
    // ---- layer 1: [N,512] -> [N,512], fp16 MFMA -> int8 gather stream ----
    k_gemm_q8<<<g512, TPB, 0, stream>>>(A16, W1f, as1, ad1, als, ald, X8, scl, 512, 512, HEADS);
    k_agg512<<<NB_AGG, TPB, 0, stream>>>(X8, scl, als, ald, offs, csr, b1, A16, bn1);
    k_bnelu<<<2048, TPB, 0, stream>>>(A16, bn1, g1, be1);
    // ---- layer 2: [N,512] -> [N,128], fp16 MFMA + fp16 gather stream ----
    k_gemm_mfma<<<g128, TPB, 0, stream>>>(A16, W2f, as2, ad2, als, ald, Bh, 512, 128, 1);
    k_agg128<<<NB_AGG, TPB, 0, stream>>>(Bh, als, ald, offs, csr, b2, C, bn2);
    // ---- fused BN+ELU + pool + classify ----
    k_poolclassify<<<N_GRAPHS, TPB, 0, stream>>>(C, bn2, g2, be2, goffs, cw1, cb1, cw2, cb2, out);
}

// Round 14
// 576.769 us; speedup vs baseline: 1.0152x; 1.0152x over previous
//
#include <hip/hip_runtime.h>

#define N_NODES 50000
#define N_PAD 50048 /* 391*128 */
#define NBY 391
#define N_EDGES 400000
#define EP (N_EDGES + N_NODES) /* 450000 with self loops */
#define N_GRAPHS 256
#define EMB 64
#define HID 128
#define HEADS 4
#define GDIM 256
#define NUM_CLASSES 20
#define EPS_BN 1e-5f
#define NEG_SLOPE 0.2f
#define NB_AGG 2048

typedef __attribute__((ext_vector_type(4))) float f32x4;
typedef _Float16 h8 __attribute__((ext_vector_type(8)));
typedef _Float16 h4 __attribute__((ext_vector_type(4)));
typedef _Float16 h2 __attribute__((ext_vector_type(2)));
typedef signed char c8 __attribute__((ext_vector_type(8)));

#define GLD(g, l)                                                              \
    __builtin_amdgcn_global_load_lds(                                          \
        (const __attribute__((address_space(1))) void*)(g),                    \
        (__attribute__((address_space(3))) void*)(l), 16, 0, 0)

// ---------------- CSR build (self-loops included) ----------------
__global__ void k_deg(const int* __restrict__ ei, int* __restrict__ deg) {
    int e = blockIdx.x * blockDim.x + threadIdx.x;
    if (e >= EP) return;
    int dst = (e < N_EDGES) ? ei[N_EDGES + e] : (e - N_EDGES);
    atomicAdd(&deg[dst], 1);
}

__global__ void k_scanA(const int* __restrict__ deg, int* __restrict__ incl, int* __restrict__ bsums) {
    __shared__ int sh[1024];
    int t = threadIdx.x;
    int i = blockIdx.x * 1024 + t;
    int v = (i < N_NODES) ? deg[i] : 0;
    int xv = v;
    sh[t] = xv;
    __syncthreads();
    for (int off = 1; off < 1024; off <<= 1) {
        int y = (t >= off) ? sh[t - off] : 0;
        __syncthreads();
        xv += y;
        sh[t] = xv;
        __syncthreads();
    }
    if (i < N_NODES) incl[i] = xv;
    if (t == 1023) bsums[blockIdx.x] = xv;
}

// scanB folded in: each block (uniform i>>10) sums the preceding block totals.
__global__ void k_scanC(const int* __restrict__ incl, const int* __restrict__ deg,
                        const int* __restrict__ bsums, int* __restrict__ offs) {
    int i = blockIdx.x * blockDim.x + threadIdx.x;
    int b = i >> 10;  // uniform within a 256-thread block
    int add = 0;
    for (int k = 0; k < b; k++) add += bsums[k];
    if (i < N_NODES) offs[i] = incl[i] - deg[i] + add;
    if (i == 0) offs[N_NODES] = EP;
}

__global__ void k_scatter(const int* __restrict__ ei, const int* __restrict__ offs,
                          int* __restrict__ cnt, int* __restrict__ csr) {
    int e = blockIdx.x * blockDim.x + threadIdx.x;
    if (e >= EP) return;
    int src, dst;
    if (e < N_EDGES) { src = ei[e]; dst = ei[N_EDGES + e]; }
    else { src = e - N_EDGES; dst = src; }
    int pos = atomicAdd(&cnt[dst], 1);
    csr[offs[dst] + pos] = src;
}

// ---------------- fused setup: fp16 weight conversions + wtil + bn/deg zeroing ----------------
__device__ __forceinline__ void cvt1(const float* __restrict__ in, _Float16* __restrict__ o, int i) {
    int f = i * 4;
    float4 v = *(const float4*)(in + f);
    h4 r;
    r[0] = (_Float16)v.x; r[1] = (_Float16)v.y; r[2] = (_Float16)v.z; r[3] = (_Float16)v.w;
    *(h4*)(o + f) = r;
}

__global__ __launch_bounds__(256) void k_setup(const float* __restrict__ W0, const float* __restrict__ as0,
                                               const float* __restrict__ ad0, const float* __restrict__ W1,
                                               const float* __restrict__ W2,
                                               _Float16* __restrict__ W0f, _Float16* __restrict__ W1f,
                                               _Float16* __restrict__ W2f,
                                               float* __restrict__ wtil,
                                               float* __restrict__ bn0, float* __restrict__ bn1,
                                               float* __restrict__ bn2,
                                               int* __restrict__ deg) {
    int b = blockIdx.x, t = threadIdx.x;
    if (b < 256) {                       // W1: 512x512 -> 65536 float4
        cvt1(W1, W1f, b * 256 + t);
    } else if (b < 288) {                // W0: 512x64 -> 8192 float4
        cvt1(W0, W0f, (b - 256) * 256 + t);
    } else if (b < 352) {                // W2: 128x512 -> 16384 float4
        cvt1(W2, W2f, (b - 288) * 256 + t);
    } else if (b == 352) {               // wtil = W0 projected onto a_src/a_dst
        int h = t >> 6, k = t & 63;
        float ss = 0.f, sd = 0.f;
        for (int c = 0; c < 128; c++) {
            float w = W0[(size_t)(h * 128 + c) * 64 + k];
            ss += w * as0[h * 128 + c];
            sd += w * ad0[h * 128 + c];
        }
        wtil[t] = ss;
        wtil[256 + t] = sd;
    } else if (b == 353) {               // zero the three BN accumulators
        for (int i = t; i < 1024; i += 256) { bn0[i] = 0.f; bn1[i] = 0.f; bn2[i] = 0.f; }
    } else {                             // zero deg+cnt (2*N_NODES ints = 25000 int4)
        int i4 = (b - 354) * 256 + t;
        if (i4 < 25000) ((int4*)deg)[i4] = make_int4(0, 0, 0, 0);
    }
}

// ---------------- fused node features + layer-0 logits + graph bounds ----------------
__global__ __launch_bounds__(256) void k_node_al0(const int* __restrict__ x,
                                                  const float* __restrict__ depth,
                                                  const float* __restrict__ emb_table,
                                                  const float* __restrict__ dw,
                                                  const float* __restrict__ db,
                                                  const float* __restrict__ wtil,
                                                  const int* __restrict__ batch,
                                                  _Float16* __restrict__ h16,
                                                  float* __restrict__ als, float* __restrict__ ald,
                                                  int* __restrict__ goffs) {
    int wid = threadIdx.x >> 6, lane = threadIdx.x & 63;
    int n = blockIdx.x * 4 + wid;
    if (n >= N_NODES) return;
    float v = emb_table[x[n] * EMB + lane] + depth[n] * dw[lane] + db[lane];
    h16[(size_t)n * 64 + lane] = (_Float16)v;
#pragma unroll
    for (int h = 0; h < 4; h++) {
        float ps = v * wtil[h * 64 + lane];
        float pd = v * wtil[256 + h * 64 + lane];
        for (int off = 32; off; off >>= 1) {
            ps += __shfl_xor(ps, off);
            pd += __shfl_xor(pd, off);
        }
        if (lane == 0) { als[n * 4 + h] = ps; ald[n * 4 + h] = pd; }
    }
    if (lane == 0) {
        int b = batch[n];
        int bp = (n == 0) ? -1 : batch[n - 1];
        for (int g = bp + 1; g <= b; g++) goffs[g] = n;
        if (n == N_NODES - 1) {
            for (int g = b + 1; g <= N_GRAPHS; g++) goffs[g] = N_NODES;
        }
    }
}

// ---------------- in-place BN+ELU on fp16 activations (M=512); 2 rows/iter ----------------
__global__ __launch_bounds__(256) void k_bnelu(_Float16* __restrict__ a,
                                               const float* __restrict__ sums,
                                               const float* __restrict__ gamma,
                                               const float* __restrict__ beta) {
    const int lane = threadIdx.x & 63;
    const int wid = threadIdx.x >> 6;
    const int c0 = lane * 8;
    const float invN = 1.f / (float)N_NODES;
    float sc[8], sh[8];
#pragma unroll
    for (int k = 0; k < 8; k += 4) {
        float4 s4 = *(const float4*)(sums + c0 + k);
        float4 q4 = *(const float4*)(sums + 512 + c0 + k);
        float4 g4 = *(const float4*)(gamma + c0 + k);
        float4 b4 = *(const float4*)(beta + c0 + k);
        float m, v;
        m = s4.x * invN; v = q4.x * invN - m * m;
        sc[k + 0] = g4.x * __frsqrt_rn(v + EPS_BN); sh[k + 0] = b4.x - m * sc[k + 0];
        m = s4.y * invN; v = q4.y * invN - m * m;
        sc[k + 1] = g4.y * __frsqrt_rn(v + EPS_BN); sh[k + 1] = b4.y - m * sc[k + 1];
        m = s4.z * invN; v = q4.z * invN - m * m;
        sc[k + 2] = g4.z * __frsqrt_rn(v + EPS_BN); sh[k + 2] = b4.z - m * sc[k + 2];
        m = s4.w * invN; v = q4.w * invN - m * m;
        sc[k + 3] = g4.w * __frsqrt_rn(v + EPS_BN); sh[k + 3] = b4.w - m * sc[k + 3];
    }
    // 2 rows per iteration (N even, start/stride even -> n+1 always valid)
    const int stride = gridDim.x * 8;
    for (int n = (blockIdx.x * 4 + wid) * 2; n < N_NODES; n += stride) {
        _Float16* p0 = a + (size_t)n * 512 + c0;
        _Float16* p1 = p0 + 512;
        h8 v0 = *(h8*)p0;
        h8 v1 = *(h8*)p1;
        h8 o0, o1;
#pragma unroll
        for (int k = 0; k < 8; k++) {
            float x0 = (float)v0[k] * sc[k] + sh[k];
            x0 = x0 > 0.f ? x0 : expm1f(x0);
            o0[k] = (_Float16)x0;
            float x1 = (float)v1[k] * sc[k] + sh[k];
            x1 = x1 > 0.f ? x1 : expm1f(x1);
            o1[k] = (_Float16)x1;
        }
        *(h8*)p0 = o0;
        *(h8*)p1 = o1;
    }
}

// layer-0 aggregate in h-space: QUARTER-WAVE per node; fp16 gather; 4-edge unroll.
__global__ __launch_bounds__(256) void k_agg0(const _Float16* __restrict__ h16,
                                              const float* __restrict__ als,
                                              const float* __restrict__ ald_g,
                                              const int* __restrict__ offs,
                                              const int* __restrict__ csr,
                                              _Float16* __restrict__ outh) {
    const int lane = threadIdx.x & 63;
    const int wwid = threadIdx.x >> 6;
    const int q = lane >> 4, l = lane & 15;
    const int gw = blockIdx.x * 4 + wwid;
    const int stride = gridDim.x * 16;
    for (int n = gw * 4 + q; n < N_NODES; n += stride) {
        int s0 = offs[n], s1 = offs[n + 1];
        float aldl = (l < 4) ? ald_g[n * 4 + l] : 0.f;
        float acc[4][4] = {};
        float den[4] = {};
        int e = s0;
        for (; e + 4 <= s1; e += 4) {
            int srcA = csr[e], srcB = csr[e + 1];
            int srcC = csr[e + 2], srcD = csr[e + 3];
            float wA = 0.f, wB = 0.f, wC = 0.f, wD = 0.f;
            if (l < 4) {
                float a1 = als[srcA * 4 + l] + aldl;
                a1 = a1 > 0.f ? a1 : NEG_SLOPE * a1;
                wA = expf(a1);
                float a2 = als[srcB * 4 + l] + aldl;
                a2 = a2 > 0.f ? a2 : NEG_SLOPE * a2;
                wB = expf(a2);
                float a3 = als[srcC * 4 + l] + aldl;
                a3 = a3 > 0.f ? a3 : NEG_SLOPE * a3;
                wC = expf(a3);
                float a4 = als[srcD * 4 + l] + aldl;
                a4 = a4 > 0.f ? a4 : NEG_SLOPE * a4;
                wD = expf(a4);
            }
            h4 vA = *(const h4*)(h16 + (size_t)srcA * 64 + l * 4);
            h4 vB = *(const h4*)(h16 + (size_t)srcB * 64 + l * 4);
            h4 vC = *(const h4*)(h16 + (size_t)srcC * 64 + l * 4);
            h4 vD = *(const h4*)(h16 + (size_t)srcD * 64 + l * 4);
            float vA0 = (float)vA[0], vA1 = (float)vA[1], vA2 = (float)vA[2], vA3 = (float)vA[3];
            float vB0 = (float)vB[0], vB1 = (float)vB[1], vB2 = (float)vB[2], vB3 = (float)vB[3];
            float vC0 = (float)vC[0], vC1 = (float)vC[1], vC2 = (float)vC[2], vC3 = (float)vC[3];
            float vD0 = (float)vD[0], vD1 = (float)vD[1], vD2 = (float)vD[2], vD3 = (float)vD[3];
#pragma unroll
            for (int h = 0; h < 4; h++) {
                float whA = __shfl(wA, q * 16 + h);
                float whB = __shfl(wB, q * 16 + h);
                float whC = __shfl(wC, q * 16 + h);
                float whD = __shfl(wD, q * 16 + h);
                den[h] += (whA + whB) + (whC + whD);
                acc[h][0] += whA * vA0 + whB * vB0 + whC * vC0 + whD * vD0;
                acc[h][1] += whA * vA1 + whB * vB1 + whC * vC1 + whD * vD1;
                acc[h][2] += whA * vA2 + whB * vB2 + whC * vC2 + whD * vD2;
                acc[h][3] += whA * vA3 + whB * vB3 + whC * vC3 + whD * vD3;
            }
        }
        for (; e < s1; e++) {
            int src = csr[e];
            float w = 0.f;
            if (l < 4) {
                float a1 = als[src * 4 + l] + aldl;
                a1 = a1 > 0.f ? a1 : NEG_SLOPE * a1;
                w = expf(a1);
            }
            h4 v = *(const h4*)(h16 + (size_t)src * 64 + l * 4);
            float v0 = (float)v[0], v1 = (float)v[1], v2 = (float)v[2], v3 = (float)v[3];
#pragma unroll
            for (int h = 0; h < 4; h++) {
                float wh = __shfl(w, q * 16 + h);
                den[h] += wh;
                acc[h][0] += wh * v0;
                acc[h][1] += wh * v1;
                acc[h][2] += wh * v2;
                acc[h][3] += wh * v3;
            }
        }
#pragma unroll
        for (int h = 0; h < 4; h++) {
            float id = 1.f / den[h];
            h4 hv;
            hv[0] = (_Float16)(acc[h][0] * id);
            hv[1] = (_Float16)(acc[h][1] * id);
            hv[2] = (_Float16)(acc[h][2] * id);
            hv[3] = (_Float16)(acc[h][3] * id);
            *(h4*)(outh + (size_t)n * 256 + h * 64 + l * 4) = hv;
        }
    }
}

// layer-0 block-diag fp16 MFMA GEMM (dbuf prefetch) + fused BN-stats epilogue
__global__ __launch_bounds__(256) void k_gemm0h(const _Float16* __restrict__ A,
                                                const _Float16* __restrict__ W,
                                                const float* __restrict__ bias,
                                                _Float16* __restrict__ outA,
                                                float* __restrict__ bnacc) {
    __shared__ h8 sA[2][512], sW[2][512];
    const int nbx = gridDim.x;
    const int d = blockIdx.y * nbx + blockIdx.x;
    const int by = (d / (8 * nbx)) * 8 + (d & 7);
    const int bx = (d >> 3) % nbx;
    if (by >= NBY) return;
    const int hd = bx;
    const int t = threadIdx.x;
    const int lane = t & 63;
    const int wid = t >> 6;
    const int wm = wid >> 1, wn = wid & 1;
    const int r0 = by * 128;
    const int l15 = lane & 15, quad = lane >> 4;
    f32x4 acc[4][4] = {};
    auto stage = [&](int buf, int kb) {
#pragma unroll
        for (int r = 0; r < 2; r++) {
            int c = r * 256 + t;
            int row = c >> 2, q = c & 3;
            size_t gA = ((size_t)(r0 + row) * 256 + hd * 64 + kb) * 2 + q * 16;
            size_t gW = ((size_t)(hd * 128 + row) * 64 + kb) * 2 + q * 16;
            GLD((const char*)A + gA, (char*)&sA[buf][0] + c * 16);
            GLD((const char*)W + gW, (char*)&sW[buf][0] + c * 16);
        }
    };
    stage(0, 0);
    __syncthreads();
#pragma unroll
    for (int ki = 0; ki < 2; ki++) {
        int cur = ki & 1;
        if (ki + 1 < 2) stage(cur ^ 1, (ki + 1) * 32);
        h8 a[4], w[4];
#pragma unroll
        for (int i = 0; i < 4; i++) {
            a[i] = sA[cur][(wm * 64 + i * 16 + l15) * 4 + quad];
            w[i] = sW[cur][(wn * 64 + i * 16 + l15) * 4 + quad];
        }
#pragma unroll
        for (int i = 0; i < 4; i++)
#pragma unroll
            for (int j = 0; j < 4; j++)
                acc[i][j] = __builtin_amdgcn_mfma_f32_16x16x32_f16(a[i], w[j], acc[i][j], 0, 0, 0);
        __syncthreads();
    }
    float colsum[4] = {}, colsq[4] = {};
#pragma unroll
    for (int i = 0; i < 4; i++) {
        int gr = r0 + wm * 64 + i * 16 + quad * 4;
#pragma unroll
        for (int j = 0; j < 4; j++) {
            int gc = hd * 128 + wn * 64 + j * 16 + l15;
            float bv = bias[gc];
#pragma unroll
            for (int rg = 0; rg < 4; rg++) {
                int rr = gr + rg;
                if (rr < N_NODES) {
                    float o = acc[i][j][rg] + bv;
                    outA[(size_t)rr * 512 + gc] = (_Float16)o;
                    colsum[j] += o;
                    colsq[j] += o * o;
                }
            }
        }
    }
#pragma unroll
    for (int j = 0; j < 4; j++) {
        colsum[j] += __shfl_xor(colsum[j], 16);
        colsum[j] += __shfl_xor(colsum[j], 32);
        colsq[j] += __shfl_xor(colsq[j], 16);
        colsq[j] += __shfl_xor(colsq[j], 32);
    }
    float* sS = (float*)&sA[0][0];
    float* sQ = (float*)&sW[0][0];
    __syncthreads();
    if (quad == 0) {
#pragma unroll
        for (int j = 0; j < 4; j++) {
            int c = wn * 64 + j * 16 + l15;
            sS[c * 2 + wm] = colsum[j];
            sQ[c * 2 + wm] = colsq[j];
        }
    }
    __syncthreads();
    if (t < 128) {
        atomicAdd(bnacc + hd * 128 + t, sS[t * 2] + sS[t * 2 + 1]);
        atomicAdd(bnacc + 512 + hd * 128 + t, sQ[t * 2] + sQ[t * 2 + 1]);
    }
}

// ---------------- layer-1 fp16 MFMA GEMM with int8 row-block-quantized output ----------------
__global__ __launch_bounds__(256) void k_gemm_q8(const _Float16* __restrict__ A,
                                                 const _Float16* __restrict__ W,
                                                 const float* __restrict__ a_src,
                                                 const float* __restrict__ a_dst,
                                                 float* __restrict__ als_g,
                                                 float* __restrict__ ald_g,
                                                 signed char* __restrict__ out8,
                                                 _Float16* __restrict__ scl,
                                                 int K, int M, int heads) {
    __shared__ h8 sA[2][512], sW[2][512];
    const int nbx = gridDim.x;
    const int d = blockIdx.y * nbx + blockIdx.x;
    const int by = (d / (8 * nbx)) * 8 + (d & 7);
    const int bx = (d >> 3) % nbx;
    if (by >= NBY) return;
    const int t = threadIdx.x;
    const int lane = t & 63;
    const int wid = t >> 6;
    const int wm = wid >> 1, wn = wid & 1;
    const int r0 = by * 128, c0 = bx * 128;
    const int l15 = lane & 15, quad = lane >> 4;
    f32x4 acc[4][4] = {};
    auto stage = [&](int buf, int kb) {
#pragma unroll
        for (int r = 0; r < 2; r++) {
            int c = r * 256 + t;
            int row = c >> 2, q = c & 3;
            size_t gA = ((size_t)(r0 + row) * K + kb) * 2 + q * 16;
            size_t gW = ((size_t)(c0 + row) * K + kb) * 2 + q * 16;
            GLD((const char*)A + gA, (char*)&sA[buf][0] + c * 16);
            GLD((const char*)W + gW, (char*)&sW[buf][0] + c * 16);
        }
    };
    stage(0, 0);
    __syncthreads();
    const int nkb = K >> 5;
    for (int ki = 0; ki < nkb; ki++) {
        int cur = ki & 1;
        if (ki + 1 < nkb) stage(cur ^ 1, (ki + 1) * 32);
        h8 a[4], w[4];
#pragma unroll
        for (int i = 0; i < 4; i++) {
            a[i] = sA[cur][(wm * 64 + i * 16 + l15) * 4 + quad];
            w[i] = sW[cur][(wn * 64 + i * 16 + l15) * 4 + quad];
        }
#pragma unroll
        for (int i = 0; i < 4; i++)
#pragma unroll
            for (int j = 0; j < 4; j++)
                acc[i][j] = __builtin_amdgcn_mfma_f32_16x16x32_f16(a[i], w[j], acc[i][j], 0, 0, 0);
        __syncthreads();
    }
    // ---- per-(row, col-block) absmax -> scale -> int8 quantize ----
    float* sAm = (float*)&sA[0][0];  // 256 floats
    {
        float amax[4][4];
#pragma unroll
        for (int i = 0; i < 4; i++)
#pragma unroll
            for (int rg = 0; rg < 4; rg++) {
                float m = 0.f;
#pragma unroll
                for (int j = 0; j < 4; j++) m = fmaxf(m, fabsf(acc[i][j][rg]));
#pragma unroll
                for (int mk = 1; mk < 16; mk <<= 1) m = fmaxf(m, __shfl_xor(m, mk));
                amax[i][rg] = m;
            }
        if (l15 == 0) {
#pragma unroll
            for (int i = 0; i < 4; i++)
#pragma unroll
                for (int rg = 0; rg < 4; rg++) {
                    int ri = wm * 64 + i * 16 + quad * 4 + rg;
                    sAm[ri * 2 + wn] = amax[i][rg];
                }
        }
    }
    __syncthreads();
#pragma unroll
    for (int i = 0; i < 4; i++) {
        int gr = r0 + wm * 64 + i * 16 + quad * 4;
#pragma unroll
        for (int rg = 0; rg < 4; rg++) {
            int ri = wm * 64 + i * 16 + quad * 4 + rg;
            float amax = fmaxf(sAm[ri * 2], sAm[ri * 2 + 1]);
            _Float16 s_h = (_Float16)(amax * (1.f / 127.f));
            float s_r = (float)s_h;
            float inv = s_r > 0.f ? 1.f / s_r : 0.f;
            int rr = gr + rg;
            if (rr < N_NODES) {
                if (wn == 0 && l15 == 0) scl[(size_t)rr * 4 + bx] = s_h;
#pragma unroll
                for (int j = 0; j < 4; j++) {
                    int gc = c0 + wn * 64 + j * 16 + l15;
                    int q = (int)rintf(acc[i][j][rg] * inv);
                    q = q > 127 ? 127 : (q < -127 ? -127 : q);
                    out8[(size_t)rr * 512 + gc] = (signed char)q;
                }
            }
        }
    }
    __syncthreads();
    // ---- exact fp32 attention-logit epilogue (unchanged) ----
    const int hd = bx;
    float ps[4][4] = {}, pd[4][4] = {};
#pragma unroll
    for (int j = 0; j < 4; j++) {
        int ch = wn * 64 + j * 16 + l15;
        float av = a_src[hd * 128 + ch];
        float dv = a_dst[hd * 128 + ch];
#pragma unroll
        for (int i = 0; i < 4; i++)
#pragma unroll
            for (int rg = 0; rg < 4; rg++) {
                ps[i][rg] += acc[i][j][rg] * av;
                pd[i][rg] += acc[i][j][rg] * dv;
            }
    }
#pragma unroll
    for (int m = 1; m < 16; m <<= 1)
#pragma unroll
        for (int i = 0; i < 4; i++)
#pragma unroll
            for (int rg = 0; rg < 4; rg++) {
                ps[i][rg] += __shfl_xor(ps[i][rg], m);
                pd[i][rg] += __shfl_xor(pd[i][rg], m);
            }
    float* sS = (float*)&sA[0][0];
    float* sD = (float*)&sW[0][0];
    if (l15 == 0) {
#pragma unroll
        for (int i = 0; i < 4; i++)
#pragma unroll
            for (int rg = 0; rg < 4; rg++) {
                int ri = wm * 64 + i * 16 + quad * 4 + rg;
                sS[ri * 2 + wn] = ps[i][rg];
                sD[ri * 2 + wn] = pd[i][rg];
            }
    }
    __syncthreads();
    if (t < 128) {
        int row = r0 + t;
        if (row < N_NODES) {
            als_g[row * heads + hd] = sS[t * 2] + sS[t * 2 + 1];
            ald_g[row * heads + hd] = sD[t * 2] + sD[t * 2 + 1];
        }
    }
}

// ---------------- fp16 MFMA GEMM (dbuf prefetch) + fused attention-logit epilogue ----------------
__global__ __launch_bounds__(256) void k_gemm_mfma(const _Float16* __restrict__ A,
                                                   const _Float16* __restrict__ W,
                                                   const float* __restrict__ a_src,
                                                   const float* __restrict__ a_dst,
                                                   float* __restrict__ als_g,
                                                   float* __restrict__ ald_g,
                                                   _Float16* __restrict__ out,
                                                   int K, int M, int heads) {
    __shared__ h8 sA[2][512], sW[2][512];
    const int nbx = gridDim.x;
    const int d = blockIdx.y * nbx + blockIdx.x;
    const int by = (d / (8 * nbx)) * 8 + (d & 7);
    const int bx = (d >> 3) % nbx;
    if (by >= NBY) return;
    const int t = threadIdx.x;
    const int lane = t & 63;
    const int wid = t >> 6;
    const int wm = wid >> 1, wn = wid & 1;
    const int r0 = by * 128, c0 = bx * 128;
    const int l15 = lane & 15, quad = lane >> 4;
    f32x4 acc[4][4] = {};
    auto stage = [&](int buf, int kb) {
#pragma unroll
        for (int r = 0; r < 2; r++) {
            int c = r * 256 + t;
            int row = c >> 2, q = c & 3;
            size_t gA = ((size_t)(r0 + row) * K + kb) * 2 + q * 16;
            size_t gW = ((size_t)(c0 + row) * K + kb) * 2 + q * 16;
            GLD((const char*)A + gA, (char*)&sA[buf][0] + c * 16);
            GLD((const char*)W + gW, (char*)&sW[buf][0] + c * 16);
        }
    };
    stage(0, 0);
    __syncthreads();
    const int nkb = K >> 5;
    for (int ki = 0; ki < nkb; ki++) {
        int cur = ki & 1;
        if (ki + 1 < nkb) stage(cur ^ 1, (ki + 1) * 32);
        h8 a[4], w[4];
#pragma unroll
        for (int i = 0; i < 4; i++) {
            a[i] = sA[cur][(wm * 64 + i * 16 + l15) * 4 + quad];
            w[i] = sW[cur][(wn * 64 + i * 16 + l15) * 4 + quad];
        }
#pragma unroll
        for (int i = 0; i < 4; i++)
#pragma unroll
            for (int j = 0; j < 4; j++)
                acc[i][j] = __builtin_amdgcn_mfma_f32_16x16x32_f16(a[i], w[j], acc[i][j], 0, 0, 0);
        __syncthreads();
    }
#pragma unroll
    for (int i = 0; i < 4; i++) {
        int gr = r0 + wm * 64 + i * 16 + quad * 4;
#pragma unroll
        for (int j = 0; j < 4; j++) {
            int gc = c0 + wn * 64 + j * 16 + l15;
#pragma unroll
            for (int rg = 0; rg < 4; rg++) {
                int rr = gr + rg;
                if (rr < N_NODES) out[(size_t)rr * M + gc] = (_Float16)acc[i][j][rg];
            }
        }
    }
    const int hd = bx;
    float ps[4][4] = {}, pd[4][4] = {};
#pragma unroll
    for (int j = 0; j < 4; j++) {
        int ch = wn * 64 + j * 16 + l15;
        float av = a_src[hd * 128 + ch];
        float dv = a_dst[hd * 128 + ch];
#pragma unroll
        for (int i = 0; i < 4; i++)
#pragma unroll
            for (int rg = 0; rg < 4; rg++) {
                ps[i][rg] += acc[i][j][rg] * av;
                pd[i][rg] += acc[i][j][rg] * dv;
            }
    }
#pragma unroll
    for (int m = 1; m < 16; m <<= 1)
#pragma unroll
        for (int i = 0; i < 4; i++)
#pragma unroll
            for (int rg = 0; rg < 4; rg++) {
                ps[i][rg] += __shfl_xor(ps[i][rg], m);
                pd[i][rg] += __shfl_xor(pd[i][rg], m);
            }
    float* sS = (float*)&sA[0][0];
    float* sD = (float*)&sW[0][0];
    if (l15 == 0) {
#pragma unroll
        for (int i = 0; i < 4; i++)
#pragma unroll
            for (int rg = 0; rg < 4; rg++) {
                int ri = wm * 64 + i * 16 + quad * 4 + rg;
                sS[ri * 2 + wn] = ps[i][rg];
                sD[ri * 2 + wn] = pd[i][rg];
            }
    }
    __syncthreads();
    if (t < 128) {
        int row = r0 + t;
        if (row < N_NODES) {
            als_g[row * heads + hd] = sS[t * 2] + sS[t * 2 + 1];
            ald_g[row * heads + hd] = sD[t * 2] + sD[t * 2 + 1];
        }
    }
}

// ---------------- layer-1 segment-softmax aggregation over int8 rows ----------------
// Dequant folded into LDS staging (s_ws = w*scale, one 8B scale load per edge);
// den computed per chunk via 16-lane group reduce over staged raw weights.
__global__ __launch_bounds__(256) void k_agg512(const signed char* __restrict__ x8,
                                                const _Float16* __restrict__ scl,
                                                const float* __restrict__ als,
                                                const float* __restrict__ ald_g,
                                                const int* __restrict__ offs,
                                                const int* __restrict__ csr,
                                                const float* __restrict__ bias,
                                                _Float16* __restrict__ out16,
                                                float* __restrict__ bnacc) {
    __shared__ float pool[4][1024];
    const int wid = threadIdx.x >> 6, lane = threadIdx.x & 63;
    int* s_src = (int*)&pool[wid][0];
    float* s_w = &pool[wid][64];      // raw softmax weights [4][64]
    float* s_ws = &pool[wid][320];    // scale-folded weights [4][64]
    const int gw = blockIdx.x * 4 + wid;
    const int nw = gridDim.x * 4;
    const int hh = lane >> 4;   // head / col-block owning cols [lane*8, lane*8+8)
    const int l15 = lane & 15;
    const int c0 = lane * 8;
    float bias8[8];
#pragma unroll
    for (int k = 0; k < 8; k++) bias8[k] = bias[c0 + k];
    float bns[8] = {}, bnq[8] = {};
    for (int n = gw; n < N_NODES; n += nw) {
        int s0 = offs[n], s1 = offs[n + 1];
        float4 aldv = *(const float4*)(ald_g + n * 4);
        float a[8] = {};
        float den = 0.f;
        for (int base = s0; base < s1; base += 64) {
            int j = base + lane;
            int srcj = 0;
            float w0 = 0.f, w1 = 0.f, w2 = 0.f, w3 = 0.f;
            float sc0 = 0.f, sc1 = 0.f, sc2 = 0.f, sc3 = 0.f;
            if (j < s1) {
                srcj = csr[j];
                float4 alv = *(const float4*)(als + srcj * 4);
                h4 sc4 = *(const h4*)(scl + (size_t)srcj * 4);
                float e0 = alv.x + aldv.x; e0 = e0 > 0.f ? e0 : NEG_SLOPE * e0;
                float e1 = alv.y + aldv.y; e1 = e1 > 0.f ? e1 : NEG_SLOPE * e1;
                float e2 = alv.z + aldv.z; e2 = e2 > 0.f ? e2 : NEG_SLOPE * e2;
                float e3 = alv.w + aldv.w; e3 = e3 > 0.f ? e3 : NEG_SLOPE * e3;
                w0 = expf(e0); w1 = expf(e1); w2 = expf(e2); w3 = expf(e3);
                sc0 = (float)sc4[0]; sc1 = (float)sc4[1];
                sc2 = (float)sc4[2]; sc3 = (float)sc4[3];
            }
            s_src[lane] = srcj;
            s_w[0 * 64 + lane] = w0;
            s_w[1 * 64 + lane] = w1;
            s_w[2 * 64 + lane] = w2;
            s_w[3 * 64 + lane] = w3;
            s_ws[0 * 64 + lane] = w0 * sc0;
            s_ws[1 * 64 + lane] = w1 * sc1;
            s_ws[2 * 64 + lane] = w2 * sc2;
            s_ws[3 * 64 + lane] = w3 * sc3;
            // den for this chunk: each 16-lane head-group sums its 64 raw weights
            {
                float4 dw = *(const float4*)&s_w[hh * 64 + l15 * 4];
                float ds = (dw.x + dw.y) + (dw.z + dw.w);
                ds += __shfl_xor(ds, 1);
                ds += __shfl_xor(ds, 2);
                ds += __shfl_xor(ds, 4);
                ds += __shfl_xor(ds, 8);
                den += ds;
            }
            int cend = min(64, s1 - base);
            int e = 0;
            for (; e + 8 <= cend; e += 8) {
                c8 v[8];
                float ws[8];
#pragma unroll
                for (int u = 0; u < 8; u++) {
                    v[u] = *(const c8*)(x8 + (size_t)s_src[e + u] * 512 + c0);
                    ws[u] = s_ws[hh * 64 + e + u];
                }
#pragma unroll
                for (int u = 0; u < 8; u++) {
#pragma unroll
                    for (int k = 0; k < 8; k++) a[k] += ws[u] * (float)v[u][k];
                }
            }
            for (; e + 2 <= cend; e += 2) {
                c8 vA = *(const c8*)(x8 + (size_t)s_src[e] * 512 + c0);
                c8 vB = *(const c8*)(x8 + (size_t)s_src[e + 1] * 512 + c0);
                float wsA = s_ws[hh * 64 + e], wsB = s_ws[hh * 64 + e + 1];
#pragma unroll
                for (int k = 0; k < 8; k++) a[k] += wsA * (float)vA[k] + wsB * (float)vB[k];
            }
            if (e < cend) {
                c8 v = *(const c8*)(x8 + (size_t)s_src[e] * 512 + c0);
                float ws = s_ws[hh * 64 + e];
#pragma unroll
                for (int k = 0; k < 8; k++) a[k] += ws * (float)v[k];
            }
        }
        float id = 1.f / den;
        h8 ov;
#pragma unroll
        for (int k = 0; k < 8; k++) {
            float o = a[k] * id + bias8[k];
            ov[k] = (_Float16)o;
            bns[k] += o;
            bnq[k] += o * o;
        }
        *(h8*)(out16 + (size_t)n * 512 + c0) = ov;
    }
#pragma unroll
    for (int k = 0; k < 8; k++) {
        pool[wid][c0 + k] = bns[k];
        pool[wid][512 + c0 + k] = bnq[k];
    }
    __syncthreads();
    for (int t = threadIdx.x; t < 1024; t += 256)
        atomicAdd(bnacc + t, pool[0][t] + pool[1][t] + pool[2][t] + pool[3][t]);
}

// ---------------- layer-2 tail aggregation (1 head, fp16 in/out) ----------------
__global__ __launch_bounds__(256) void k_agg128(const _Float16* __restrict__ xf,
                                                const float* __restrict__ als,
                                                const float* __restrict__ ald_g,
                                                const int* __restrict__ offs,
                                                const int* __restrict__ csr,
                                                const float* __restrict__ bias,
                                                _Float16* __restrict__ out_h,
                                                float* __restrict__ bnacc) {
    __shared__ float pool[4][256];
    const int wid = threadIdx.x >> 6, lane = threadIdx.x & 63;
    int* s_src = (int*)&pool[wid][0];
    float* s_w = &pool[wid][64];
    const int gw = blockIdx.x * 4 + wid;
    const int nw = gridDim.x * 4;
    const int c = lane * 2;
    const float2 biasv = *(const float2*)(bias + c);
    float bns0 = 0.f, bns1 = 0.f, bnq0 = 0.f, bnq1 = 0.f;
    for (int n = gw; n < N_NODES; n += nw) {
        int s0 = offs[n], s1 = offs[n + 1];
        float aldv = ald_g[n];
        float ax = 0.f, ay = 0.f, den = 0.f;
        for (int base = s0; base < s1; base += 64) {
            int j = base + lane;
            int srcj = 0;
            float alv = 0.f;
            if (j < s1) { srcj = csr[j]; alv = als[srcj]; }
            float e0 = alv + aldv;
            e0 = e0 > 0.f ? e0 : NEG_SLOPE * e0;
            s_src[lane] = srcj;
            s_w[lane] = expf(e0);
            int cend = min(64, s1 - base);
            int e = 0;
            for (; e + 8 <= cend; e += 8) {
                h2 v[8];
                float w[8];
#pragma unroll
                for (int u = 0; u < 8; u++) {
                    v[u] = *(const h2*)(xf + (size_t)s_src[e + u] * 128 + c);
                    w[u] = s_w[e + u];
                }
#pragma unroll
                for (int u = 0; u < 8; u++) {
                    den += w[u];
                    ax += w[u] * (float)v[u][0];
                    ay += w[u] * (float)v[u][1];
                }
            }
            for (; e < cend; e++) {
                h2 v = *(const h2*)(xf + (size_t)s_src[e] * 128 + c);
                float w = s_w[e];
                den += w;
                ax += w * (float)v[0];
                ay += w * (float)v[1];
            }
        }
        float id = 1.f / den;
        float ox = ax * id + biasv.x;
        float oy = ay * id + biasv.y;
        h2 oh;
        oh[0] = (_Float16)ox;
        oh[1] = (_Float16)oy;
        *(h2*)(out_h + (size_t)n * 128 + c) = oh;
        bns0 += ox; bnq0 += ox * ox;
        bns1 += oy; bnq1 += oy * oy;
    }
    pool[wid][c] = bns0; pool[wid][c + 1] = bns1;
    pool[wid][128 + c] = bnq0; pool[wid][128 + c + 1] = bnq1;
    __syncthreads();
    {
        int t = threadIdx.x;
        atomicAdd(bnacc + t, pool[0][t] + pool[1][t] + pool[2][t] + pool[3][t]);
    }
}

// ---------------- fused BN+ELU + mean/max pool + classifier (fp16 C) ----------------
__global__ __launch_bounds__(256) void k_poolclassify(const _Float16* __restrict__ C,
                                                      const float* __restrict__ bnsums,
                                                      const float* __restrict__ gamma,
                                                      const float* __restrict__ beta,
                                                      const int* __restrict__ goffs,
                                                      const float* __restrict__ cw1, const float* __restrict__ cb1,
                                                      const float* __restrict__ cw2, const float* __restrict__ cb2,
                                                      float* __restrict__ out) {
    __shared__ float er[256];
    __shared__ float red[256];
    int g = blockIdx.x, t = threadIdx.x;
    int c = t & 127, half = t >> 7;
    const float invN = 1.f / (float)N_NODES;
    float m = bnsums[c] * invN;
    float var = bnsums[128 + c] * invN - m * m;
    float sc = gamma[c] * __frsqrt_rn(var + EPS_BN);
    float sh = beta[c] - m * sc;
    int s = goffs[g], e = goffs[g + 1];
    float sum = 0.f, mx = -INFINITY;
    for (int n = s + half; n < e; n += 2) {
        float x = (float)C[(size_t)n * 128 + c] * sc + sh;
        x = x > 0.f ? x : expm1f(x);
        sum += x;
        mx = fmaxf(mx, x);
    }
    red[t] = sum;
    __syncthreads();
    float sumT = red[c] + red[128 + c];
    __syncthreads();
    red[t] = mx;
    __syncthreads();
    float mxT = fmaxf(red[c], red[128 + c]);
    int cnt = e - s;
    if (half == 0) {
        er[c] = sumT / (float)max(cnt, 1);
        er[128 + c] = mxT;
    }
    __syncthreads();
    float acc = cb1[t];
    for (int k = 0; k < 256; k++) acc += er[k] * cw1[t * 256 + k];
    __syncthreads();
    red[t] = fmaxf(acc, 0.f);
    __syncthreads();
    if (t < NUM_CLASSES) {
        float o = cb2[t];
        for (int k = 0; k < 256; k++) o += red[k] * cw2[t * 256 + k];
        out[g * NUM_CLASSES + t] = o;
    }
}

// ---------------- driver ----------------
extern "C" void kernel_launch(void* const* d_in, const int* in_sizes, int n_in,
                              void* d_out, int out_size, void* d_ws, size_t ws_size,
                              hipStream_t stream) {
    (void)in_sizes; (void)n_in; (void)out_size; (void)ws_size;
    const int* x = (const int*)d_in[0];
    const int* ei = (const int*)d_in[1];
    const float* depth = (const float*)d_in[2];
    const int* batch = (const int*)d_in[3];
    const float* emb_table = (const float*)d_in[4];
    const float* depth_w = (const float*)d_in[5];
    const float* depth_b = (const float*)d_in[6];
    const float* W0 = (const float*)d_in[7];
    const float* as0 = (const float*)d_in[8];
    const float* ad0 = (const float*)d_in[9];
    const float* b0 = (const float*)d_in[10];
    const float* g0 = (const float*)d_in[11];
    const float* be0 = (const float*)d_in[12];
    const float* W1 = (const float*)d_in[13];
    const float* as1 = (const float*)d_in[14];
    const float* ad1 = (const float*)d_in[15];
    const float* b1 = (const float*)d_in[16];
    const float* g1 = (const float*)d_in[17];
    const float* be1 = (const float*)d_in[18];
    const float* W2 = (const float*)d_in[19];
    const float* as2 = (const float*)d_in[20];
    const float* ad2 = (const float*)d_in[21];
    const float* b2 = (const float*)d_in[22];
    const float* g2 = (const float*)d_in[23];
    const float* be2 = (const float*)d_in[24];
    const float* cw1 = (const float*)d_in[25];
    const float* cb1 = (const float*)d_in[26];
    const float* cw2 = (const float*)d_in[27];
    const float* cb2 = (const float*)d_in[28];
    float* out = (float*)d_out;

    // workspace carve (~106 MB, well under the proven ws_size >= 211,469,440 B)
    size_t off = 0;
    char* base = (char*)d_ws;
    auto carve = [&](size_t bytes) -> void* {
        void* p = base + off;
        off += (bytes + 255) & ~(size_t)255;
        return p;
    };
    // B region (51.2 MB): layer-0 {h16 [N,64] fp16 | hth [N_PAD,256] fp16};
    // layer-1 {x8 int8 [N,512] (25.6MB) | scales fp16 [N,4] @+26MB};
    // layer-2 GEMM out fp16 [N,128] (12.8MB, x8 dead by then).
    float* B = (float*)carve((size_t)N_NODES * 512 * 2);
    _Float16* A16 = (_Float16*)carve((size_t)N_PAD * 512 * 2);  // 51.25 MB
    _Float16* W0f = (_Float16*)carve((size_t)512 * 64 * 2);
    _Float16* W1f = (_Float16*)carve((size_t)512 * 512 * 2);
    _Float16* W2f = (_Float16*)carve((size_t)128 * 512 * 2);
    float* als = (float*)carve((size_t)N_NODES * HEADS * 4);
    float* ald = (float*)carve((size_t)N_NODES * HEADS * 4);
    float* bn0 = (float*)carve(1024 * 4);
    float* bn1 = (float*)carve(1024 * 4);
    float* bn2 = (float*)carve(1024 * 4);
    float* wtil = (float*)carve(512 * 4);
    int* deg = (int*)carve((size_t)2 * N_NODES * 4);  // deg + cnt contiguous (zeroed in k_setup)
    int* cnt = deg + N_NODES;
    int* incl = (int*)carve((size_t)N_NODES * 4);
    int* offs = (int*)carve((size_t)(N_NODES + 1) * 4);
    int* bsums = (int*)carve(64 * 4);
    int* csr = (int*)carve((size_t)EP * 4);
    int* goffs = (int*)carve((size_t)(N_GRAPHS + 1) * 4);

    _Float16* h16 = (_Float16*)B;
    _Float16* hth = (_Float16*)((char*)B + (size_t)N_NODES * 64 * 2);
    signed char* X8 = (signed char*)B;                              // layer-1 int8 stream
    _Float16* scl = (_Float16*)((char*)B + (26u << 20));            // 400 KB scale table
    _Float16* Bh = (_Float16*)B;                                    // layer-2 fp16 [N,128]
    _Float16* C = (_Float16*)A16;     // layer-2 fp16 scratch reuses A16 region

    const int TPB = 256;
    int gbN = (N_NODES + TPB - 1) / TPB;
    int gbE = (EP + TPB - 1) / TPB;
    int nbScan = (N_NODES + 1023) / 1024;
    int gbNode4 = (N_NODES + 3) / 4;
    dim3 g512(4, 392);  // swizzled: 392 = ceil(391/8)*8
    dim3 g128(1, 391);

    k_setup<<<452, TPB, 0, stream>>>(W0, as0, ad0, W1, W2, W0f, W1f, W2f, wtil,
                                     bn0, bn1, bn2, deg);
    k_deg<<<gbE, TPB, 0, stream>>>(ei, deg);
    k_scanA<<<nbScan, 1024, 0, stream>>>(deg, incl, bsums);
    k_scanC<<<gbN, TPB, 0, stream>>>(incl, deg, bsums, offs);
    k_scatter<<<gbE, TPB, 0, stream>>>(ei, offs, cnt, csr);

    // ---- layer 0 (fused node features + logits + graph bounds; h-space aggregation) ----
    k_node_al0<<<gbNode4, TPB, 0, stream>>>(x, depth, emb_table, depth_w, depth_b, wtil,
                                            batch, h16, als, ald, goffs);
    k_agg0<<<NB_AGG, TPB, 0, stream>>>(h16, als, ald, offs, csr, hth);
    k_gemm0h<<<g512, TPB, 0, stream>>>(hth, W0f, b0, A16, bn0);
    k_bnelu<<<2048, TPB, 0, stream>>>(A16, bn0, g0, be0);
    // ---- layer 1: [N,512] -> [N,512], fp16 MFMA -> int8 gather stream ----
    k_gemm_q8<<<g512, TPB, 0, stream>>>(A16, W1f, as1, ad1, als, ald, X8, scl, 512, 512, HEADS);
    k_agg512<<<NB_AGG, TPB, 0, stream>>>(X8, scl, als, ald, offs, csr, b1, A16, bn1);
    k_bnelu<<<2048, TPB, 0, stream>>>(A16, bn1, g1, be1);
    // ---- layer 2: [N,512] -> [N,128], fp16 MFMA + fp16 gather stream ----
    k_gemm_mfma<<<g128, TPB, 0, stream>>>(A16, W2f, as2, ad2, als, ald, Bh, 512, 128, 1);
    k_agg128<<<NB_AGG, TPB, 0, stream>>>(Bh, als, ald, offs, csr, b2, C, bn2);
    // ---- fused BN+ELU + pool + classify ----
    k_poolclassify<<<N_GRAPHS, TPB, 0, stream>>>(C, bn2, g2, be2, goffs, cw1, cb1, cw2, cb2, out);
}